// Round 5
// baseline (65.822 us; speedup 1.0000x reference)
//
#include <hip/hip_runtime.h>
#include <hip/hip_bf16.h>

#define B_N   256
#define IN_N  1024
#define OUT_N 512
#define P_N   1000
#define NS_N  128

#define K1P   3072   // padded K of GEMM1 (3*P_N)
#define N1P   1024   // padded N of GEMM1
#define K2P   1024   // padded K of GEMM2
#define SK1   16     // split-K GEMM1
#define SK2   8      // split-K GEMM2

typedef __attribute__((ext_vector_type(8))) short short8v;
typedef __attribute__((ext_vector_type(4))) float f32x4;
typedef unsigned short ushort_t;

__device__ __forceinline__ float sigmoid_f(float z) { return 1.0f / (1.0f + __expf(-z)); }

__device__ __forceinline__ void split1(float x, ushort_t& h, ushort_t& l) {
    __hip_bfloat16 hb = __float2bfloat16(x);
    float r = x - __bfloat162float(hb);
    __hip_bfloat16 lb = __float2bfloat16(r);
    h = __bfloat16_as_ushort(hb);
    l = __bfloat16_as_ushort(lb);
}

__device__ __forceinline__ void split8(float4 v0, float4 v1, short8v& h, short8v& l) {
    float vv[8] = {v0.x, v0.y, v0.z, v0.w, v1.x, v1.y, v1.z, v1.w};
    #pragma unroll
    for (int j = 0; j < 8; ++j) {
        ushort_t hh, ll;
        split1(vv[j], hh, ll);
        h[j] = (short)hh;
        l[j] = (short)ll;
    }
}

// ---- K1: SDE partial reduction over a 64-step time-half, float4 columns ----
// For half th: SE_th = sum_{s in half} eps; LL_th = sum r^{(half_end)-s} eps.
// FF = eps[s=0] (written by th==0 blocks).
__global__ __launch_bounds__(128) void sde_partial_kernel(const float* __restrict__ noise,
                                                          const float* __restrict__ decay_param,
                                                          float* __restrict__ SE,
                                                          float* __restrict__ LL,
                                                          float* __restrict__ FF) {
    const int b  = blockIdx.x;
    const int ch = blockIdx.y;    // column half: 0 -> cols 0..511, 1 -> 512..1023
    const int th = blockIdx.z;    // time half: 0 -> steps 0..63, 1 -> 64..127
    const int t  = threadIdx.x;
    const int c0 = ch * 512 + t * 4;
    if (c0 >= P_N) return;        // P_N = 1000 = 4*250, no partial float4

    float decay = sigmoid_f(decay_param[0]) * 0.5f;
    const float dt = 1.0f / NS_N;
    float retain = 1.0f - decay * dt;

    const float* base = noise + (size_t)b * NS_N * P_N + c0;
    const int s0 = th * 64;

    float4 sE = {0, 0, 0, 0}, L = {0, 0, 0, 0};
    float rp = 1.0f;              // retain^{(s0+63)-s}, s descending
    #pragma unroll 16
    for (int s = s0 + 63; s >= s0; --s) {
        float4 e = *(const float4*)(base + (size_t)s * P_N);
        sE.x += e.x; sE.y += e.y; sE.z += e.z; sE.w += e.w;
        L.x += rp * e.x; L.y += rp * e.y; L.z += rp * e.z; L.w += rp * e.w;
        rp *= retain;
    }

    size_t o = ((size_t)th * B_N + b) * 1024 + c0;
    *(float4*)(SE + o) = sE;
    *(float4*)(LL + o) = L;
    if (th == 0) *(float4*)(FF + (size_t)b * 1024 + c0) = *(const float4*)base;   // eps[0]
}

// ---- K2: combine halves + feedback dot -> T as bf16 hi/lo [B_N][K1P] ----
// L = LL1 + retain^64 * LL0; sumE = SE0 + SE1; A = (sumE - retain*L)/(decay*dt)
// T[b,3c+k]: k=0 -> scale*(A-L), k=1 -> scale*A, k=2 -> scale*(A-F)
__global__ __launch_bounds__(256) void combine_kernel(const float* __restrict__ x,
                                                      const float* __restrict__ fb_w,
                                                      const float* __restrict__ fb_b,
                                                      const float* __restrict__ decay_param,
                                                      const float* __restrict__ SE,
                                                      const float* __restrict__ LL,
                                                      const float* __restrict__ FF,
                                                      ushort_t* __restrict__ Thi,
                                                      ushort_t* __restrict__ Tlo) {
    const int b = blockIdx.x;
    const int t = threadIdx.x;

    // feedback dot-product
    float4 xv = ((const float4*)(x + (size_t)b * IN_N))[t];
    float4 wv = ((const float4*)fb_w)[t];
    float s = xv.x * wv.x + xv.y * wv.y + xv.z * wv.z + xv.w * wv.w;
    __shared__ float red[256];
    red[t] = s;
    __syncthreads();
    for (int off = 128; off >= 1; off >>= 1) {
        if (t < off) red[t] += red[t + off];
        __syncthreads();
    }
    float fbv = sigmoid_f(red[0] + fb_b[0]);

    float decay = sigmoid_f(decay_param[0]) * 0.5f;
    const float dt = 1.0f / NS_N;
    float retain = 1.0f - decay * dt;
    float inv_omr = 1.0f / (decay * dt);
    float r2 = retain * retain, r4 = r2 * r2, r8 = r4 * r4;
    float r16 = r8 * r8, r32 = r16 * r16, r64 = r32 * r32;

    const int c0 = t * 4;
    size_t tb = (size_t)b * K1P + 3 * (size_t)c0;
    if (c0 >= P_N) {              // t in 250..255 -> padding
        #pragma unroll
        for (int j = 0; j < 12; ++j) { Thi[tb + j] = 0; Tlo[tb + j] = 0; }
        return;
    }

    size_t o0 = ((size_t)0 * B_N + b) * 1024 + c0;
    size_t o1 = ((size_t)1 * B_N + b) * 1024 + c0;
    float4 se0 = *(const float4*)(SE + o0);
    float4 se1 = *(const float4*)(SE + o1);
    float4 ll0 = *(const float4*)(LL + o0);
    float4 ll1 = *(const float4*)(LL + o1);
    float4 ff  = *(const float4*)(FF + (size_t)b * 1024 + c0);

    float sd = sqrtf(dt);
    float scale = fbv * sd * (1.0f / NS_N);

    float Se[4] = {se0.x + se1.x, se0.y + se1.y, se0.z + se1.z, se0.w + se1.w};
    float Lv[4] = {ll1.x + r64 * ll0.x, ll1.y + r64 * ll0.y, ll1.z + r64 * ll0.z, ll1.w + r64 * ll0.w};
    float Fv[4] = {ff.x, ff.y, ff.z, ff.w};

    #pragma unroll
    for (int j = 0; j < 4; ++j) {
        float Aj = (Se[j] - retain * Lv[j]) * inv_omr;
        float t0 = scale * (Aj - Lv[j]);
        float t1 = scale * Aj;
        float t2 = scale * (Aj - Fv[j]);
        ushort_t h, l;
        split1(t0, h, l); Thi[tb + 3 * j + 0] = h; Tlo[tb + 3 * j + 0] = l;
        split1(t1, h, l); Thi[tb + 3 * j + 1] = h; Tlo[tb + 3 * j + 1] = l;
        split1(t2, h, l); Thi[tb + 3 * j + 2] = h; Tlo[tb + 3 * j + 2] = l;
    }
}

// ---- K3: GEMM1 — A pre-split bf16 hi/lo, B f32 split on the fly ----
// C = (Ahi+Alo)[M,K] * B[N,K]^T (3-term, drop lo*lo). BM=BN=128, BK=64.
// 512 threads = 8 waves in 2(row)x4(col); wave tile 64x32 = 4x2 frags of 16x16.
// LDS XOR-swizzled at 16B granules: slot(row,g) holds granule g^(row&7).
__global__ __launch_bounds__(512) void gemm_hilo_mfma(const ushort_t* __restrict__ Ahi,
                                                      const ushort_t* __restrict__ Alo,
                                                      const float* __restrict__ B,
                                                      float* __restrict__ Cpart,
                                                      int lda, int ldb,
                                                      int Nvalid, int Kvalid,
                                                      int Kper, int ldc) {
    __shared__ __align__(16) ushort_t As_hi[128 * 64];
    __shared__ __align__(16) ushort_t As_lo[128 * 64];
    __shared__ __align__(16) ushort_t Bs_hi[128 * 64];
    __shared__ __align__(16) ushort_t Bs_lo[128 * 64];

    const int tid  = threadIdx.x;
    const int lane = tid & 63;
    const int wave = tid >> 6;
    const int r15  = lane & 15;
    const int g4   = lane >> 4;
    const int wrow = wave >> 2;
    const int wcol = wave & 3;
    const int n0 = blockIdx.x * 128;
    const int m0 = blockIdx.y * 128;
    const size_t kbeg = (size_t)blockIdx.z * Kper;

    f32x4 acc[4][2] = {};

    for (int kt = 0; kt < Kper; kt += 64) {
        const size_t kk0 = kbeg + kt;
        #pragma unroll
        for (int c = 0; c < 2; ++c) {
            int chunk = tid + c * 512;
            int row = chunk >> 3;
            int g   = chunk & 7;
            int ldsoff = row * 64 + ((g ^ (row & 7)) << 3);

            const size_t ka = (size_t)(m0 + row) * lda + kk0 + g * 8;
            *(short8v*)&As_hi[ldsoff] = *(const short8v*)(Ahi + ka);
            *(short8v*)&As_lo[ldsoff] = *(const short8v*)(Alo + ka);

            float4 b0 = {0, 0, 0, 0}, b1 = {0, 0, 0, 0};
            if ((n0 + row) < Nvalid && (int)(kk0 + g * 8) < Kvalid) {
                const float* bp = B + (size_t)(n0 + row) * ldb + kk0 + g * 8;
                b0 = *(const float4*)bp;
                b1 = *(const float4*)(bp + 4);
            }
            short8v bh, bl;
            split8(b0, b1, bh, bl);
            *(short8v*)&Bs_hi[ldsoff] = bh;
            *(short8v*)&Bs_lo[ldsoff] = bl;
        }
        __syncthreads();

        #pragma unroll
        for (int ks = 0; ks < 2; ++ks) {
            const int g = ks * 4 + g4;
            short8v ah[4], al[4], bh[2], bl[2];
            #pragma unroll
            for (int f = 0; f < 4; ++f) {
                int arow = wrow * 64 + f * 16 + r15;
                int aoff = arow * 64 + ((g ^ (arow & 7)) << 3);
                ah[f] = *(const short8v*)&As_hi[aoff];
                al[f] = *(const short8v*)&As_lo[aoff];
            }
            #pragma unroll
            for (int f = 0; f < 2; ++f) {
                int brow = wcol * 32 + f * 16 + r15;
                int boff = brow * 64 + ((g ^ (brow & 7)) << 3);
                bh[f] = *(const short8v*)&Bs_hi[boff];
                bl[f] = *(const short8v*)&Bs_lo[boff];
            }
            #pragma unroll
            for (int mf = 0; mf < 4; ++mf) {
                #pragma unroll
                for (int nf = 0; nf < 2; ++nf) {
                    acc[mf][nf] = __builtin_amdgcn_mfma_f32_16x16x32_bf16(ah[mf], bh[nf], acc[mf][nf], 0, 0, 0);
                    acc[mf][nf] = __builtin_amdgcn_mfma_f32_16x16x32_bf16(ah[mf], bl[nf], acc[mf][nf], 0, 0, 0);
                    acc[mf][nf] = __builtin_amdgcn_mfma_f32_16x16x32_bf16(al[mf], bh[nf], acc[mf][nf], 0, 0, 0);
                }
            }
        }
        __syncthreads();
    }

    // C/D mapping: col = lane&15, row = (lane>>4)*4 + reg  [m89-verified]
    float* cp = Cpart + (size_t)blockIdx.z * 256 * ldc;
    #pragma unroll
    for (int mf = 0; mf < 4; ++mf) {
        #pragma unroll
        for (int nf = 0; nf < 2; ++nf) {
            #pragma unroll
            for (int r = 0; r < 4; ++r) {
                int m = m0 + wrow * 64 + mf * 16 + g4 * 4 + r;
                int n = n0 + wcol * 32 + nf * 16 + r15;
                cp[(size_t)m * ldc + n] = acc[mf][nf][r];
            }
        }
    }
}

// ---- K4: GEMM2 with fused split-K-reduce of GEMM1 partials in A-staging ----
// agg[m,k] = conv_b[k] + sum_z Cpart1[z][m][k]; C2 = agg * out_w^T.
__global__ __launch_bounds__(512) void gemm2_fused_kernel(const float* __restrict__ Cpart1,
                                                          const float* __restrict__ conv_b,
                                                          const float* __restrict__ out_w,
                                                          float* __restrict__ Cpart2) {
    __shared__ __align__(16) ushort_t As_hi[128 * 64];
    __shared__ __align__(16) ushort_t As_lo[128 * 64];
    __shared__ __align__(16) ushort_t Bs_hi[128 * 64];
    __shared__ __align__(16) ushort_t Bs_lo[128 * 64];

    const int tid  = threadIdx.x;
    const int lane = tid & 63;
    const int wave = tid >> 6;
    const int r15  = lane & 15;
    const int g4   = lane >> 4;
    const int wrow = wave >> 2;
    const int wcol = wave & 3;
    const int n0 = blockIdx.x * 128;       // OUT cols (512 / 128 = 4)
    const int m0 = blockIdx.y * 128;       // batch rows (256 / 128 = 2)
    const int kbeg = blockIdx.z * (K2P / SK2);   // 128 per z

    f32x4 acc[4][2] = {};

    for (int kt = 0; kt < K2P / SK2; kt += 64) {
        const int kk0 = kbeg + kt;
        #pragma unroll
        for (int c = 0; c < 2; ++c) {
            int chunk = tid + c * 512;
            int row = chunk >> 3;
            int g   = chunk & 7;
            int ldsoff = row * 64 + ((g ^ (row & 7)) << 3);
            int k = kk0 + g * 8;

            // A: sum 16 partials (+ conv_b where valid)
            float4 a0 = {0, 0, 0, 0}, a1 = {0, 0, 0, 0};
            {
                const float* cp = Cpart1 + (size_t)(m0 + row) * N1P + k;
                #pragma unroll
                for (int z = 0; z < SK1; ++z) {
                    float4 p0 = *(const float4*)(cp + (size_t)z * (B_N * N1P));
                    float4 p1 = *(const float4*)(cp + (size_t)z * (B_N * N1P) + 4);
                    a0.x += p0.x; a0.y += p0.y; a0.z += p0.z; a0.w += p0.w;
                    a1.x += p1.x; a1.y += p1.y; a1.z += p1.z; a1.w += p1.w;
                }
                if (k < P_N) {                       // k multiple of 8; P_N=1000 -> whole granule valid
                    float4 c0v = *(const float4*)(conv_b + k);
                    float4 c1v = *(const float4*)(conv_b + k + 4);
                    a0.x += c0v.x; a0.y += c0v.y; a0.z += c0v.z; a0.w += c0v.w;
                    a1.x += c1v.x; a1.y += c1v.y; a1.z += c1v.z; a1.w += c1v.w;
                }
            }
            short8v ah, al;
            split8(a0, a1, ah, al);
            *(short8v*)&As_hi[ldsoff] = ah;
            *(short8v*)&As_lo[ldsoff] = al;

            // B: out_w [512][1000], guard k
            float4 b0 = {0, 0, 0, 0}, b1 = {0, 0, 0, 0};
            if (k < P_N) {
                const float* bp = out_w + (size_t)(n0 + row) * P_N + k;
                b0 = *(const float4*)bp;
                b1 = *(const float4*)(bp + 4);
            }
            short8v bh, bl;
            split8(b0, b1, bh, bl);
            *(short8v*)&Bs_hi[ldsoff] = bh;
            *(short8v*)&Bs_lo[ldsoff] = bl;
        }
        __syncthreads();

        #pragma unroll
        for (int ks = 0; ks < 2; ++ks) {
            const int g = ks * 4 + g4;
            short8v ah[4], al[4], bh[2], bl[2];
            #pragma unroll
            for (int f = 0; f < 4; ++f) {
                int arow = wrow * 64 + f * 16 + r15;
                int aoff = arow * 64 + ((g ^ (arow & 7)) << 3);
                ah[f] = *(const short8v*)&As_hi[aoff];
                al[f] = *(const short8v*)&As_lo[aoff];
            }
            #pragma unroll
            for (int f = 0; f < 2; ++f) {
                int brow = wcol * 32 + f * 16 + r15;
                int boff = brow * 64 + ((g ^ (brow & 7)) << 3);
                bh[f] = *(const short8v*)&Bs_hi[boff];
                bl[f] = *(const short8v*)&Bs_lo[boff];
            }
            #pragma unroll
            for (int mf = 0; mf < 4; ++mf) {
                #pragma unroll
                for (int nf = 0; nf < 2; ++nf) {
                    acc[mf][nf] = __builtin_amdgcn_mfma_f32_16x16x32_bf16(ah[mf], bh[nf], acc[mf][nf], 0, 0, 0);
                    acc[mf][nf] = __builtin_amdgcn_mfma_f32_16x16x32_bf16(ah[mf], bl[nf], acc[mf][nf], 0, 0, 0);
                    acc[mf][nf] = __builtin_amdgcn_mfma_f32_16x16x32_bf16(al[mf], bh[nf], acc[mf][nf], 0, 0, 0);
                }
            }
        }
        __syncthreads();
    }

    float* cp = Cpart2 + (size_t)blockIdx.z * (B_N * OUT_N);
    #pragma unroll
    for (int mf = 0; mf < 4; ++mf) {
        #pragma unroll
        for (int nf = 0; nf < 2; ++nf) {
            #pragma unroll
            for (int r = 0; r < 4; ++r) {
                int m = m0 + wrow * 64 + mf * 16 + g4 * 4 + r;
                int n = n0 + wcol * 32 + nf * 16 + r15;
                cp[(size_t)m * OUT_N + n] = acc[mf][nf][r];
            }
        }
    }
}

// ---- K5: reduce GEMM2 partials + bias -> final f32 output ----
__global__ __launch_bounds__(256) void reduce_out_kernel(const float* __restrict__ Cpart2,
                                                         const float* __restrict__ out_b,
                                                         float* __restrict__ out) {
    int idx = blockIdx.x * 256 + threadIdx.x;   // < 256*512
    int n = idx & (OUT_N - 1);
    float s = out_b[n];
    #pragma unroll
    for (int z = 0; z < SK2; ++z) s += Cpart2[(size_t)z * (B_N * OUT_N) + idx];
    out[idx] = s;
}

extern "C" void kernel_launch(void* const* d_in, const int* in_sizes, int n_in,
                              void* d_out, int out_size, void* d_ws, size_t ws_size,
                              hipStream_t stream) {
    const float* x           = (const float*)d_in[0];
    const float* noise       = (const float*)d_in[1];
    const float* fb_w        = (const float*)d_in[2];
    const float* fb_b        = (const float*)d_in[3];
    const float* decay_param = (const float*)d_in[4];
    const float* conv_w      = (const float*)d_in[5];  // [P][3P] flat NT layout
    const float* conv_b      = (const float*)d_in[6];
    const float* out_w       = (const float*)d_in[7];  // [OUT, P]
    const float* out_b       = (const float*)d_in[8];
    float* out = (float*)d_out;

    // workspace carve (16B-aligned)
    char* ws = (char*)d_ws;
    size_t off = 0;
    float*    SE     = (float*)(ws + off);    off += (size_t)2 * B_N * 1024 * 4;        // 2.1 MB
    float*    LL     = (float*)(ws + off);    off += (size_t)2 * B_N * 1024 * 4;        // 2.1 MB
    float*    FF     = (float*)(ws + off);    off += (size_t)B_N * 1024 * 4;            // 1.0 MB
    ushort_t* Thi    = (ushort_t*)(ws + off); off += (size_t)B_N * K1P * 2;             // 1.57 MB
    ushort_t* Tlo    = (ushort_t*)(ws + off); off += (size_t)B_N * K1P * 2;
    float*    Cpart1 = (float*)(ws + off);    off += (size_t)SK1 * B_N * N1P * 4;       // 16.8 MB
    float*    Cpart2 = (float*)(ws + off);    off += (size_t)SK2 * B_N * OUT_N * 4;     // 4.2 MB

    // K1: SDE partial reduction (256 b x 2 col-halves x 2 time-halves)
    {
        dim3 grid(B_N, 2, 2);
        sde_partial_kernel<<<grid, 128, 0, stream>>>(noise, decay_param, SE, LL, FF);
    }

    // K2: combine + feedback -> T hi/lo [256][3072]
    combine_kernel<<<B_N, 256, 0, stream>>>(x, fb_w, fb_b, decay_param, SE, LL, FF, Thi, Tlo);

    // K3: GEMM1: Cpart1 = T[256,3072] * conv_w[1000,3000]^T, split-K=16
    {
        dim3 grid(N1P / 128, B_N / 128, SK1);     // 8 x 2 x 16
        gemm_hilo_mfma<<<grid, 512, 0, stream>>>(Thi, Tlo, conv_w, Cpart1,
                                                 K1P, 3 * P_N, P_N, 3 * P_N,
                                                 K1P / SK1, N1P);
    }

    // K4: GEMM2 (fused agg-reduce + bias in A-staging), split-K=8
    {
        dim3 grid(OUT_N / 128, B_N / 128, SK2);   // 4 x 2 x 8
        gemm2_fused_kernel<<<grid, 512, 0, stream>>>(Cpart1, conv_b, out_w, Cpart2);
    }

    // K5: reduce GEMM2 partials + out_b -> out
    reduce_out_kernel<<<(B_N * OUT_N) / 256, 256, 0, stream>>>(Cpart2, out_b, out);
}

// Round 6
// 52.601 us; speedup vs baseline: 1.2513x; 1.2513x over previous
//
#include <hip/hip_runtime.h>
#include <hip/hip_bf16.h>

#define B_N   256
#define IN_N  1024
#define OUT_N 512
#define P_N   1000
#define NS_N  128

#define K1P   3072   // padded K of GEMM1 (3*P_N)
#define N1P   1024   // padded N of GEMM1
#define K2P   1024   // padded K of GEMM2
#define SK1   16     // split-K GEMM1
#define SK2   8      // split-K GEMM2

typedef __attribute__((ext_vector_type(8))) short short8v;
typedef __attribute__((ext_vector_type(4))) float f32x4;
typedef unsigned short ushort_t;

__device__ __forceinline__ float sigmoid_f(float z) { return 1.0f / (1.0f + __expf(-z)); }

__device__ __forceinline__ ushort_t f2bf(float x) {
    return __bfloat16_as_ushort(__float2bfloat16(x));
}

// ---- K1: fused feedback + SDE reduction -> T bf16 [B_N][K1P] (zero-padded) ----
// Block (b, ch): cols [ch*512, ch*512+512). 256 thr = 128 col-groups x 2 time-halves.
// Each thread reduces 64 steps with float4 loads (16 B/lane, coalesced).
// L = LL1 + retain^64*LL0; sumE = SE0+SE1; A = (sumE - retain*L)/(decay*dt); F = eps[0].
// T[b,3c+k]: k=0 -> scale*(A-L), k=1 -> scale*A, k=2 -> scale*(A-F); scale = fb*sd/NS.
__global__ __launch_bounds__(256) void sde_fused_kernel(const float* __restrict__ x,
                                                        const float* __restrict__ fb_w,
                                                        const float* __restrict__ fb_b,
                                                        const float* __restrict__ noise,
                                                        const float* __restrict__ decay_param,
                                                        ushort_t* __restrict__ Thi) {
    const int b  = blockIdx.x;
    const int ch = blockIdx.y;
    const int t  = threadIdx.x;
    const int cg = t & 127;       // col group (4 floats)
    const int th = t >> 7;        // time half

    // feedback dot-product for this batch row (all 256 threads)
    float4 xv = ((const float4*)(x + (size_t)b * IN_N))[t];
    float4 wv = ((const float4*)fb_w)[t];
    float s = xv.x * wv.x + xv.y * wv.y + xv.z * wv.z + xv.w * wv.w;
    __shared__ float red[256];
    red[t] = s;
    __syncthreads();
    for (int off = 128; off >= 1; off >>= 1) {
        if (t < off) red[t] += red[t + off];
        __syncthreads();
    }
    float fbv = sigmoid_f(red[0] + fb_b[0]);

    float decay = sigmoid_f(decay_param[0]) * 0.5f;
    const float dt = 1.0f / NS_N;
    float retain = 1.0f - decay * dt;
    float inv_omr = 1.0f / (decay * dt);
    float r2 = retain * retain, r4 = r2 * r2, r8 = r4 * r4;
    float r16 = r8 * r8, r32 = r16 * r16, r64 = r32 * r32;

    const int c0 = ch * 512 + cg * 4;
    const bool act = (c0 < P_N);          // P_N = 1000, multiple of 4

    float4 sE = {0, 0, 0, 0}, L = {0, 0, 0, 0}, F = {0, 0, 0, 0};
    if (act) {
        const float* base = noise + (size_t)b * NS_N * P_N + c0;
        const int s0 = th * 64;
        float rp = 1.0f;                  // retain^{(s0+63)-s}, s descending
        #pragma unroll 16
        for (int ss = s0 + 63; ss >= s0; --ss) {
            float4 e = *(const float4*)(base + (size_t)ss * P_N);
            sE.x += e.x; sE.y += e.y; sE.z += e.z; sE.w += e.w;
            L.x += rp * e.x; L.y += rp * e.y; L.z += rp * e.z; L.w += rp * e.w;
            if (ss == 0) F = e;           // only th==0 reaches ss==0
            rp *= retain;
        }
    }

    __shared__ float4 xSE[128], xL[128], xF[128];
    if (th == 0) { xSE[cg] = sE; xL[cg] = L; xF[cg] = F; }
    __syncthreads();

    if (th == 1) {
        size_t tb = (size_t)b * K1P + 3 * (size_t)c0;
        if (!act) {
            #pragma unroll
            for (int j = 0; j < 12; ++j) Thi[tb + j] = 0;
            return;
        }
        float4 se0 = xSE[cg], ll0 = xL[cg], ff = xF[cg];
        float Se[4] = {se0.x + sE.x, se0.y + sE.y, se0.z + sE.z, se0.w + sE.w};
        float Lv[4] = {L.x + r64 * ll0.x, L.y + r64 * ll0.y, L.z + r64 * ll0.z, L.w + r64 * ll0.w};
        float Fv[4] = {ff.x, ff.y, ff.z, ff.w};
        float sd = sqrtf(dt);
        float scale = fbv * sd * (1.0f / NS_N);
        #pragma unroll
        for (int j = 0; j < 4; ++j) {
            float Aj = (Se[j] - retain * Lv[j]) * inv_omr;
            Thi[tb + 3 * j + 0] = f2bf(scale * (Aj - Lv[j]));
            Thi[tb + 3 * j + 1] = f2bf(scale * Aj);
            Thi[tb + 3 * j + 2] = f2bf(scale * (Aj - Fv[j]));
        }
    }
}

// ---- bf16 MFMA NT GEMM: A pre-converted bf16, B f32 converted on the fly ----
// C = A[M,K] * B[N,K]^T. BM=BN=128, BK=64. 512 thr = 8 waves in 2(row)x4(col);
// wave tile 64x32 = 4x2 frags of 16x16x32.
// LDS XOR-swizzled at 16B granules: slot(row,g) holds granule g^(row&7).
__global__ __launch_bounds__(512) void gemm_bf16_mfma(const ushort_t* __restrict__ A,
                                                      const float* __restrict__ B,
                                                      float* __restrict__ Cpart,
                                                      int lda, int ldb,
                                                      int Nvalid, int Kvalid,
                                                      int Kper, int ldc) {
    __shared__ __align__(16) ushort_t As[128 * 64];
    __shared__ __align__(16) ushort_t Bs[128 * 64];

    const int tid  = threadIdx.x;
    const int lane = tid & 63;
    const int wave = tid >> 6;
    const int r15  = lane & 15;
    const int g4   = lane >> 4;
    const int wrow = wave >> 2;
    const int wcol = wave & 3;
    const int n0 = blockIdx.x * 128;
    const int m0 = blockIdx.y * 128;
    const size_t kbeg = (size_t)blockIdx.z * Kper;

    f32x4 acc[4][2] = {};

    for (int kt = 0; kt < Kper; kt += 64) {
        const size_t kk0 = kbeg + kt;
        #pragma unroll
        for (int c = 0; c < 2; ++c) {
            int chunk = tid + c * 512;        // 0..1023
            int row = chunk >> 3;             // 0..127
            int g   = chunk & 7;              // 16B granule (8 elems)
            int ldsoff = row * 64 + ((g ^ (row & 7)) << 3);

            const size_t ka = (size_t)(m0 + row) * lda + kk0 + g * 8;
            *(short8v*)&As[ldsoff] = *(const short8v*)(A + ka);

            short8v bh = {0, 0, 0, 0, 0, 0, 0, 0};
            if ((n0 + row) < Nvalid && (int)(kk0 + g * 8) < Kvalid) {
                const float* bp = B + (size_t)(n0 + row) * ldb + kk0 + g * 8;
                float4 b0 = *(const float4*)bp;
                float4 b1 = *(const float4*)(bp + 4);
                bh[0] = (short)f2bf(b0.x); bh[1] = (short)f2bf(b0.y);
                bh[2] = (short)f2bf(b0.z); bh[3] = (short)f2bf(b0.w);
                bh[4] = (short)f2bf(b1.x); bh[5] = (short)f2bf(b1.y);
                bh[6] = (short)f2bf(b1.z); bh[7] = (short)f2bf(b1.w);
            }
            *(short8v*)&Bs[ldsoff] = bh;
        }
        __syncthreads();

        #pragma unroll
        for (int ks = 0; ks < 2; ++ks) {
            const int g = ks * 4 + g4;        // k-granule 0..7
            short8v af[4], bf_[2];
            #pragma unroll
            for (int f = 0; f < 4; ++f) {
                int arow = wrow * 64 + f * 16 + r15;
                af[f] = *(const short8v*)&As[arow * 64 + ((g ^ (arow & 7)) << 3)];
            }
            #pragma unroll
            for (int f = 0; f < 2; ++f) {
                int brow = wcol * 32 + f * 16 + r15;
                bf_[f] = *(const short8v*)&Bs[brow * 64 + ((g ^ (brow & 7)) << 3)];
            }
            #pragma unroll
            for (int mf = 0; mf < 4; ++mf) {
                #pragma unroll
                for (int nf = 0; nf < 2; ++nf) {
                    acc[mf][nf] = __builtin_amdgcn_mfma_f32_16x16x32_bf16(af[mf], bf_[nf], acc[mf][nf], 0, 0, 0);
                }
            }
        }
        __syncthreads();
    }

    // C/D mapping: col = lane&15, row = (lane>>4)*4 + reg  [m89-verified]
    float* cp = Cpart + (size_t)blockIdx.z * B_N * ldc;
    #pragma unroll
    for (int mf = 0; mf < 4; ++mf) {
        #pragma unroll
        for (int nf = 0; nf < 2; ++nf) {
            #pragma unroll
            for (int r = 0; r < 4; ++r) {
                int m = m0 + wrow * 64 + mf * 16 + g4 * 4 + r;
                int n = n0 + wcol * 32 + nf * 16 + r15;
                cp[(size_t)m * ldc + n] = acc[mf][nf][r];
            }
        }
    }
}

// ---- reduce GEMM1 partials + conv_b -> agg bf16 [B_N][K2P] (zero-padded) ----
__global__ __launch_bounds__(256) void reduce_agg_kernel(const float* __restrict__ Cpart1,
                                                         const float* __restrict__ conv_b,
                                                         ushort_t* __restrict__ agg) {
    int idx = blockIdx.x * 256 + threadIdx.x;   // < 256*1024
    int n = idx & (N1P - 1);
    float s = 0.f;
    if (n < P_N) {
        s = conv_b[n];
        #pragma unroll
        for (int z = 0; z < SK1; ++z) s += Cpart1[(size_t)z * (B_N * N1P) + idx];
    }
    agg[idx] = f2bf(s);
}

// ---- reduce GEMM2 partials + out_b -> final f32 output ----
__global__ __launch_bounds__(256) void reduce_out_kernel(const float* __restrict__ Cpart2,
                                                         const float* __restrict__ out_b,
                                                         float* __restrict__ out) {
    int idx = blockIdx.x * 256 + threadIdx.x;   // < 256*512
    int n = idx & (OUT_N - 1);
    float s = out_b[n];
    #pragma unroll
    for (int z = 0; z < SK2; ++z) s += Cpart2[(size_t)z * (B_N * OUT_N) + idx];
    out[idx] = s;
}

extern "C" void kernel_launch(void* const* d_in, const int* in_sizes, int n_in,
                              void* d_out, int out_size, void* d_ws, size_t ws_size,
                              hipStream_t stream) {
    const float* x           = (const float*)d_in[0];
    const float* noise       = (const float*)d_in[1];
    const float* fb_w        = (const float*)d_in[2];
    const float* fb_b        = (const float*)d_in[3];
    const float* decay_param = (const float*)d_in[4];
    const float* conv_w      = (const float*)d_in[5];  // [P][3P] flat NT layout
    const float* conv_b      = (const float*)d_in[6];
    const float* out_w       = (const float*)d_in[7];  // [OUT, P]
    const float* out_b       = (const float*)d_in[8];
    float* out = (float*)d_out;

    // workspace carve (16B-aligned)
    char* ws = (char*)d_ws;
    size_t off = 0;
    ushort_t* Thi    = (ushort_t*)(ws + off); off += (size_t)B_N * K1P * 2;         // 1.57 MB
    ushort_t* agg    = (ushort_t*)(ws + off); off += (size_t)B_N * K2P * 2;         // 0.52 MB
    float*    Cpart1 = (float*)(ws + off);    off += (size_t)SK1 * B_N * N1P * 4;   // 16.8 MB
    float*    Cpart2 = (float*)(ws + off);    off += (size_t)SK2 * B_N * OUT_N * 4; // 4.2 MB

    // K1: fused feedback + SDE reduction -> T bf16 [256][3072]
    {
        dim3 grid(B_N, 2);
        sde_fused_kernel<<<grid, 256, 0, stream>>>(x, fb_w, fb_b, noise, decay_param, Thi);
    }

    // K2: GEMM1: Cpart1 = T[256,3072] * conv_w[1000,3000]^T, split-K=16
    {
        dim3 grid(N1P / 128, B_N / 128, SK1);     // 8 x 2 x 16
        gemm_bf16_mfma<<<grid, 512, 0, stream>>>(Thi, conv_w, Cpart1,
                                                 K1P, 3 * P_N, P_N, 3 * P_N,
                                                 K1P / SK1, N1P);
    }

    // K3: reduce partials + conv_b -> agg bf16 [256][1024]
    reduce_agg_kernel<<<(B_N * N1P) / 256, 256, 0, stream>>>(Cpart1, conv_b, agg);

    // K4: GEMM2: Cpart2 = agg[256,1024] * out_w[512,1000]^T, split-K=8
    {
        dim3 grid(OUT_N / 128, B_N / 128, SK2);   // 4 x 2 x 8
        gemm_bf16_mfma<<<grid, 512, 0, stream>>>(agg, out_w, Cpart2,
                                                 K2P, P_N, OUT_N, P_N,
                                                 K2P / SK2, OUT_N);
    }

    // K5: reduce GEMM2 partials + out_b -> out
    reduce_out_kernel<<<(B_N * OUT_N) / 256, 256, 0, stream>>>(Cpart2, out_b, out);
}

// Round 7
// 48.386 us; speedup vs baseline: 1.3604x; 1.0871x over previous
//
#include <hip/hip_runtime.h>
#include <hip/hip_bf16.h>

#define B_N   256
#define IN_N  1024
#define OUT_N 512
#define P_N   1000
#define NS_N  128

#define K1P   3072   // padded K of GEMM1 (3*P_N)
#define N1P   1024   // padded N of GEMM1
#define K2P   1024   // padded K of GEMM2
#define SK1   16     // split-K GEMM1
#define SK2   8      // split-K GEMM2

typedef __attribute__((ext_vector_type(8))) short short8v;
typedef __attribute__((ext_vector_type(4))) float f32x4;
typedef unsigned short ushort_t;
typedef __attribute__((ext_vector_type(4))) unsigned short ushort4v;

__device__ __forceinline__ float sigmoid_f(float z) { return 1.0f / (1.0f + __expf(-z)); }

__device__ __forceinline__ ushort_t f2bf(float x) {
    return __bfloat16_as_ushort(__float2bfloat16(x));
}
__device__ __forceinline__ float bf2f(ushort_t h) {
    union { unsigned u; float f; } v; v.u = ((unsigned)h) << 16;
    return v.f;
}

// ---- K1: fused feedback + SDE reduction -> T bf16 [B_N][K1P] (zero-padded) ----
// Block (b, ch): cols [ch*512, ch*512+512). 512 thr = 128 col-groups x 4 time-quarters.
// Each thread reduces 32 steps with float4 loads. Exact recombination:
// L = L3 + r32*L2 + r64*L1 + r96*L0; sumE = sum SEq; A = (sumE - retain*L)/(decay*dt).
// T[b,3c+k]: k=0 -> scale*(A-L), k=1 -> scale*A, k=2 -> scale*(A-F); scale = fb*sd/NS.
__global__ __launch_bounds__(512) void sde_fused_kernel(const float* __restrict__ x,
                                                        const float* __restrict__ fb_w,
                                                        const float* __restrict__ fb_b,
                                                        const float* __restrict__ noise,
                                                        const float* __restrict__ decay_param,
                                                        ushort_t* __restrict__ Thi) {
    const int b  = blockIdx.x;
    const int ch = blockIdx.y;
    const int t  = threadIdx.x;
    const int cg = t & 127;       // col group (4 floats)
    const int tq = t >> 7;        // time quarter 0..3

    // feedback dot-product (512 threads x float2 over 1024)
    float2 xv = ((const float2*)(x + (size_t)b * IN_N))[t];
    float2 wv = ((const float2*)fb_w)[t];
    __shared__ float red[512];
    red[t] = xv.x * wv.x + xv.y * wv.y;
    __syncthreads();
    for (int off = 256; off >= 1; off >>= 1) {
        if (t < off) red[t] += red[t + off];
        __syncthreads();
    }
    float fbv = sigmoid_f(red[0] + fb_b[0]);

    float decay = sigmoid_f(decay_param[0]) * 0.5f;
    const float dt = 1.0f / NS_N;
    float retain = 1.0f - decay * dt;
    float inv_omr = 1.0f / (decay * dt);
    float r2 = retain * retain, r4 = r2 * r2, r8 = r4 * r4;
    float r16 = r8 * r8, r32 = r16 * r16;
    float r64 = r32 * r32, r96 = r64 * r32;

    const int c0 = ch * 512 + cg * 4;
    const bool act = (c0 < P_N);          // P_N = 1000, multiple of 4
    const float* base = noise + (size_t)b * NS_N * P_N + (act ? c0 : 0);

    float4 sE = {0, 0, 0, 0}, L = {0, 0, 0, 0};
    if (act) {
        const int s0 = tq * 32;
        float rp = 1.0f;                  // retain^{(s0+31)-s}, s descending
        #pragma unroll 8
        for (int ss = s0 + 31; ss >= s0; --ss) {
            float4 e = *(const float4*)(base + (size_t)ss * P_N);
            sE.x += e.x; sE.y += e.y; sE.z += e.z; sE.w += e.w;
            L.x += rp * e.x; L.y += rp * e.y; L.z += rp * e.z; L.w += rp * e.w;
            rp *= retain;
        }
    }

    __shared__ float4 xSE[3][128], xL[3][128], xF[128];
    if (tq < 3) { xSE[tq][cg] = sE; xL[tq][cg] = L; }
    if (tq == 0 && act) xF[cg] = *(const float4*)base;   // eps[0] (L1-hot)
    __syncthreads();

    if (tq == 3) {
        size_t tb = (size_t)b * K1P + 3 * (size_t)c0;
        if (!act) {
            #pragma unroll
            for (int j = 0; j < 12; ++j) Thi[tb + j] = 0;
            return;
        }
        float4 se0 = xSE[0][cg], se1 = xSE[1][cg], se2 = xSE[2][cg];
        float4 l0 = xL[0][cg], l1 = xL[1][cg], l2 = xL[2][cg], ff = xF[cg];
        float Se[4] = {se0.x + se1.x + se2.x + sE.x, se0.y + se1.y + se2.y + sE.y,
                       se0.z + se1.z + se2.z + sE.z, se0.w + se1.w + se2.w + sE.w};
        float Lv[4] = {L.x + r32 * l2.x + r64 * l1.x + r96 * l0.x,
                       L.y + r32 * l2.y + r64 * l1.y + r96 * l0.y,
                       L.z + r32 * l2.z + r64 * l1.z + r96 * l0.z,
                       L.w + r32 * l2.w + r64 * l1.w + r96 * l0.w};
        float Fv[4] = {ff.x, ff.y, ff.z, ff.w};
        float sd = sqrtf(dt);
        float scale = fbv * sd * (1.0f / NS_N);
        #pragma unroll
        for (int j = 0; j < 4; ++j) {
            float Aj = (Se[j] - retain * Lv[j]) * inv_omr;
            Thi[tb + 3 * j + 0] = f2bf(scale * (Aj - Lv[j]));
            Thi[tb + 3 * j + 1] = f2bf(scale * Aj);
            Thi[tb + 3 * j + 2] = f2bf(scale * (Aj - Fv[j]));
        }
    }
}

// ---- bf16 MFMA NT GEMM, BM=256 (full M), BN=128, BK=64, split-K -> bf16 partials ----
// A [256][lda] bf16 dense; B [Nvalid][ldb] f32 (row/col guarded), cvt on the fly.
// 512 thr = 8 waves as 4(row)x2(col); wave tile 64x64 = 4x4 frags of 16x16x32.
// LDS XOR-swizzled at 16B granules: slot(row,g) holds granule g^(row&7).
__global__ __launch_bounds__(512) void gemm_bf16_bm256(const ushort_t* __restrict__ A,
                                                       const float* __restrict__ B,
                                                       ushort_t* __restrict__ Cpart,
                                                       int lda, int ldb,
                                                       int Nvalid, int Kvalid,
                                                       int Kper, int ldc) {
    __shared__ __align__(16) ushort_t As[256 * 64];   // 32 KB
    __shared__ __align__(16) ushort_t Bs[128 * 64];   // 16 KB

    const int tid  = threadIdx.x;
    const int lane = tid & 63;
    const int wave = tid >> 6;
    const int r15  = lane & 15;
    const int g4   = lane >> 4;
    const int wrow = wave >> 1;       // 0..3 -> rows wrow*64
    const int wcol = wave & 1;        // 0..1 -> cols wcol*64
    const int n0 = blockIdx.x * 128;
    const size_t kbeg = (size_t)blockIdx.z * Kper;

    f32x4 acc[4][4] = {};

    for (int kt = 0; kt < Kper; kt += 64) {
        const size_t kk0 = kbeg + kt;
        // stage A: 256 rows x 8 granules = 2048 chunks, 4/thread
        #pragma unroll
        for (int c = 0; c < 4; ++c) {
            int chunk = tid + c * 512;
            int row = chunk >> 3;             // 0..255
            int g   = chunk & 7;
            int ldsoff = row * 64 + ((g ^ (row & 7)) << 3);
            *(short8v*)&As[ldsoff] = *(const short8v*)(A + (size_t)row * lda + kk0 + g * 8);
        }
        // stage B: 128 rows x 8 granules = 1024 chunks, 2/thread
        #pragma unroll
        for (int c = 0; c < 2; ++c) {
            int chunk = tid + c * 512;
            int row = chunk >> 3;             // 0..127
            int g   = chunk & 7;
            int ldsoff = row * 64 + ((g ^ (row & 7)) << 3);
            int k = (int)kk0 + g * 8;
            short8v bh = {0, 0, 0, 0, 0, 0, 0, 0};
            if ((n0 + row) < Nvalid && k < Kvalid) {
                const float* bp = B + (size_t)(n0 + row) * ldb + k;
                float4 b0 = *(const float4*)bp;
                float4 b1 = *(const float4*)(bp + 4);
                bh[0] = (short)f2bf(b0.x); bh[1] = (short)f2bf(b0.y);
                bh[2] = (short)f2bf(b0.z); bh[3] = (short)f2bf(b0.w);
                bh[4] = (short)f2bf(b1.x); bh[5] = (short)f2bf(b1.y);
                bh[6] = (short)f2bf(b1.z); bh[7] = (short)f2bf(b1.w);
            }
            *(short8v*)&Bs[ldsoff] = bh;
        }
        __syncthreads();

        #pragma unroll
        for (int ks = 0; ks < 2; ++ks) {
            const int g = ks * 4 + g4;        // k-granule 0..7
            short8v af[4], bf_[4];
            #pragma unroll
            for (int f = 0; f < 4; ++f) {
                int arow = wrow * 64 + f * 16 + r15;
                af[f] = *(const short8v*)&As[arow * 64 + ((g ^ (arow & 7)) << 3)];
            }
            #pragma unroll
            for (int f = 0; f < 4; ++f) {
                int brow = wcol * 64 + f * 16 + r15;
                bf_[f] = *(const short8v*)&Bs[brow * 64 + ((g ^ (brow & 7)) << 3)];
            }
            #pragma unroll
            for (int mf = 0; mf < 4; ++mf) {
                #pragma unroll
                for (int nf = 0; nf < 4; ++nf) {
                    acc[mf][nf] = __builtin_amdgcn_mfma_f32_16x16x32_bf16(af[mf], bf_[nf], acc[mf][nf], 0, 0, 0);
                }
            }
        }
        __syncthreads();
    }

    // C/D mapping: col = lane&15, row = (lane>>4)*4 + reg  [m89-verified]
    ushort_t* cp = Cpart + (size_t)blockIdx.z * B_N * ldc;
    #pragma unroll
    for (int mf = 0; mf < 4; ++mf) {
        #pragma unroll
        for (int nf = 0; nf < 4; ++nf) {
            #pragma unroll
            for (int r = 0; r < 4; ++r) {
                int m = wrow * 64 + mf * 16 + g4 * 4 + r;
                int n = n0 + wcol * 64 + nf * 16 + r15;
                cp[(size_t)m * ldc + n] = f2bf(acc[mf][nf][r]);
            }
        }
    }
}

// ---- reduce GEMM1 bf16 partials + conv_b -> agg bf16 [B_N][K2P] (zero-padded) ----
__global__ __launch_bounds__(256) void reduce_agg_kernel(const ushort_t* __restrict__ Cpart1,
                                                         const float* __restrict__ conv_b,
                                                         ushort_t* __restrict__ agg) {
    int idx4 = (blockIdx.x * 256 + threadIdx.x) * 4;    // < 256*1024
    int n = idx4 & (N1P - 1);                           // multiple of 4
    float s0 = 0.f, s1 = 0.f, s2 = 0.f, s3 = 0.f;
    if (n < P_N) {                                      // P_N multiple of 4
        float4 cb = *(const float4*)(conv_b + n);
        s0 = cb.x; s1 = cb.y; s2 = cb.z; s3 = cb.w;
        #pragma unroll
        for (int z = 0; z < SK1; ++z) {
            ushort4v p = *(const ushort4v*)(Cpart1 + (size_t)z * (B_N * N1P) + idx4);
            s0 += bf2f(p[0]); s1 += bf2f(p[1]); s2 += bf2f(p[2]); s3 += bf2f(p[3]);
        }
    }
    ushort4v o = {f2bf(s0), f2bf(s1), f2bf(s2), f2bf(s3)};
    *(ushort4v*)(agg + idx4) = o;
}

// ---- reduce GEMM2 bf16 partials + out_b -> final f32 output ----
__global__ __launch_bounds__(256) void reduce_out_kernel(const ushort_t* __restrict__ Cpart2,
                                                         const float* __restrict__ out_b,
                                                         float* __restrict__ out) {
    int idx4 = (blockIdx.x * 256 + threadIdx.x) * 4;    // < 256*512
    int n = idx4 & (OUT_N - 1);
    float4 ob = *(const float4*)(out_b + n);
    float s0 = ob.x, s1 = ob.y, s2 = ob.z, s3 = ob.w;
    #pragma unroll
    for (int z = 0; z < SK2; ++z) {
        ushort4v p = *(const ushort4v*)(Cpart2 + (size_t)z * (B_N * OUT_N) + idx4);
        s0 += bf2f(p[0]); s1 += bf2f(p[1]); s2 += bf2f(p[2]); s3 += bf2f(p[3]);
    }
    float4 o = {s0, s1, s2, s3};
    *(float4*)(out + idx4) = o;
}

extern "C" void kernel_launch(void* const* d_in, const int* in_sizes, int n_in,
                              void* d_out, int out_size, void* d_ws, size_t ws_size,
                              hipStream_t stream) {
    const float* x           = (const float*)d_in[0];
    const float* noise       = (const float*)d_in[1];
    const float* fb_w        = (const float*)d_in[2];
    const float* fb_b        = (const float*)d_in[3];
    const float* decay_param = (const float*)d_in[4];
    const float* conv_w      = (const float*)d_in[5];  // [P][3P] flat NT layout
    const float* conv_b      = (const float*)d_in[6];
    const float* out_w       = (const float*)d_in[7];  // [OUT, P]
    const float* out_b       = (const float*)d_in[8];
    float* out = (float*)d_out;

    // workspace carve (16B-aligned)
    char* ws = (char*)d_ws;
    size_t off = 0;
    ushort_t* Thi    = (ushort_t*)(ws + off); off += (size_t)B_N * K1P * 2;          // 1.57 MB
    ushort_t* agg    = (ushort_t*)(ws + off); off += (size_t)B_N * K2P * 2;          // 0.52 MB
    ushort_t* Cpart1 = (ushort_t*)(ws + off); off += (size_t)SK1 * B_N * N1P * 2;    // 8.4 MB
    ushort_t* Cpart2 = (ushort_t*)(ws + off); off += (size_t)SK2 * B_N * OUT_N * 2;  // 2.1 MB

    // K1: fused feedback + SDE reduction -> T bf16 [256][3072]
    {
        dim3 grid(B_N, 2);
        sde_fused_kernel<<<grid, 512, 0, stream>>>(x, fb_w, fb_b, noise, decay_param, Thi);
    }

    // K2: GEMM1: Cpart1 = T[256,3072] * conv_w[1000,3000]^T, BM=256, split-K=16
    {
        dim3 grid(N1P / 128, 1, SK1);             // 8 x 1 x 16
        gemm_bf16_bm256<<<grid, 512, 0, stream>>>(Thi, conv_w, Cpart1,
                                                  K1P, 3 * P_N, P_N, 3 * P_N,
                                                  K1P / SK1, N1P);
    }

    // K3: reduce partials + conv_b -> agg bf16 [256][1024]
    reduce_agg_kernel<<<(B_N * N1P) / 1024, 256, 0, stream>>>(Cpart1, conv_b, agg);

    // K4: GEMM2: Cpart2 = agg[256,1024] * out_w[512,1000]^T, BM=256, split-K=8
    {
        dim3 grid(OUT_N / 128, 1, SK2);           // 4 x 1 x 8
        gemm_bf16_bm256<<<grid, 512, 0, stream>>>(agg, out_w, Cpart2,
                                                  K2P, P_N, OUT_N, P_N,
                                                  K2P / SK2, OUT_N);
    }

    // K5: reduce GEMM2 partials + out_b -> out
    reduce_out_kernel<<<(B_N * OUT_N) / 1024, 256, 0, stream>>>(Cpart2, out_b, out);
}